// Round 2
// baseline (51.785 us; speedup 1.0000x reference)
//
#include <hip/hip_runtime.h>
#include <math.h>

#define BN 256
#define BLOCK 512

__device__ __forceinline__ float wred_sum(float v) {
#pragma unroll
  for (int m = 32; m >= 1; m >>= 1) v += __shfl_xor(v, m, 64);
  return v;
}

template<int P, int Q>
__device__ __forceinline__ void jrot(float K[3][3], float V[3][3]) {
  float apq = K[P][Q];
  if (apq == 0.f) return;
  float app = K[P][P], aqq = K[Q][Q];
  float tau = (aqq - app) / (2.f * apq);
  float st = sqrtf(1.f + tau * tau);
  float tt = (tau >= 0.f) ? 1.f / (tau + st) : 1.f / (tau - st);
  float c = 1.f / sqrtf(1.f + tt * tt);
  float s = tt * c;
#pragma unroll
  for (int k = 0; k < 3; k++) { float kp = K[k][P], kq = K[k][Q]; K[k][P] = c * kp - s * kq; K[k][Q] = s * kp + c * kq; }
#pragma unroll
  for (int k = 0; k < 3; k++) { float kp = K[P][k], kq = K[Q][k]; K[P][k] = c * kp - s * kq; K[Q][k] = s * kp + c * kq; }
#pragma unroll
  for (int k = 0; k < 3; k++) { float vp = V[k][P], vq = V[k][Q]; V[k][P] = c * vp - s * vq; V[k][Q] = s * vp + c * vq; }
}

template<int A, int C>
__device__ __forceinline__ void cswap(float lam[3], float V[3][3]) {
  if (lam[A] < lam[C]) {
    float tl = lam[A]; lam[A] = lam[C]; lam[C] = tl;
#pragma unroll
    for (int k = 0; k < 3; k++) { float tv = V[k][A]; V[k][A] = V[k][C]; V[k][C] = tv; }
  }
}

extern "C" __global__ void __launch_bounds__(BLOCK, 4)
svdhead_kernel(const float* __restrict__ src,
               const float* __restrict__ tgt,
               const float* __restrict__ scores,
               const int* __restrict__ idx0,   // harness passes integer inputs as int32
               float* __restrict__ out)
{
  __shared__ __align__(16) float Af[6][BN];   // [0..2]=count*kpts1_d, [3..5]=kpts1_d
  __shared__ float kx[3][BN];                 // kpts0
  __shared__ float vmaskS[BN];
  __shared__ int cnt[BN];
  __shared__ float bacc[31];  // 0..8 P_v, 9..17 P_f, 18..20 Sc, 21..23 Scf, 24..26 Sxv, 27..29 Sxf, 30 M

  const int t = threadIdx.x;
  const int b = blockIdx.x;
  const int lane = t & 63;
  const int wave = t >> 6;

  if (t < 31) bacc[t] = 0.f;
  if (t < BN) cnt[t] = 0;
  __syncthreads();

  float x0 = 0.f, x1 = 0.f, x2 = 0.f, vf = 0.f;
  if (t < BN) {
    int id = idx0[(size_t)b * BN + t];        // values in [0, 256]; 256 == SENTINEL
    int valid = ((unsigned)id < 256u);
    vf = valid ? 1.f : 0.f;
    if (valid) atomicAdd(&cnt[id], 1);
    const float* sb = src + (size_t)b * 3 * BN;
    const float* tb = tgt + (size_t)b * 3 * BN;
    x0 = sb[t]; x1 = sb[BN + t]; x2 = sb[2 * BN + t];
    kx[0][t] = x0; kx[1][t] = x1; kx[2][t] = x2;
    vmaskS[t] = vf;
    Af[3][t] = tb[t]; Af[4][t] = tb[BN + t]; Af[5][t] = tb[2 * BN + t];
  }
  // block reductions for M, Sxv, Sxf (threads >= BN contribute zeros)
  {
    float r0 = wred_sum(vf);
    float r1 = wred_sum(vf * x0);
    float r2 = wred_sum(vf * x1);
    float r3 = wred_sum(vf * x2);
    float r4 = wred_sum(x0);
    float r5 = wred_sum(x1);
    float r6 = wred_sum(x2);
    if (lane == 0) {
      atomicAdd(&bacc[30], r0);
      atomicAdd(&bacc[24], r1); atomicAdd(&bacc[25], r2); atomicAdd(&bacc[26], r3);
      atomicAdd(&bacc[27], r4); atomicAdd(&bacc[28], r5); atomicAdd(&bacc[29], r6);
    }
  }
  __syncthreads();
  if (t < BN) {
    float cf = (float)cnt[t];
    Af[0][t] = cf * Af[3][t];
    Af[1][t] = cf * Af[4][t];
    Af[2][t] = cf * Af[5][t];
  }
  __syncthreads();

  // cache this lane's A fragments in registers (loop-invariant)
  const int j0 = lane * 4;
  float4 a6[6];
#pragma unroll
  for (int k = 0; k < 6; k++) a6[k] = *(const float4*)&Af[k][j0];

  float acc[24];
#pragma unroll
  for (int k = 0; k < 24; k++) acc[k] = 0.f;

  const float* srow = scores + (size_t)b * BN * BN;
  const int p0 = wave * (BN / 8);   // 32 rows per wave

  float4 xv = *(const float4*)(srow + (size_t)p0 * BN + j0);
  for (int i = 0; i < BN / 8; i++) {
    int p = p0 + i;
    float4 nxt = xv;
    if (i + 1 < BN / 8) nxt = *(const float4*)(srow + (size_t)(p + 1) * BN + j0);
    float e0 = __expf(xv.x), e1 = __expf(xv.y), e2 = __expf(xv.z), e3 = __expf(xv.w);
    float pd[6];
#pragma unroll
    for (int k = 0; k < 6; k++)
      pd[k] = e0 * a6[k].x + e1 * a6[k].y + e2 * a6[k].z + e3 * a6[k].w;
    float S = wred_sum((e0 + e1) + (e2 + e3));
    float inv = 1.f / S;
    float pvf = vmaskS[p];
    float g0 = kx[0][p], g1 = kx[1][p], g2 = kx[2][p];
    float gv = pvf * inv;
    acc[18] += gv * pd[0]; acc[19] += gv * pd[1]; acc[20] += gv * pd[2];
    acc[21] += inv * pd[3]; acc[22] += inv * pd[4]; acc[23] += inv * pd[5];
    float a0 = gv * g0, a1 = gv * g1, a2 = gv * g2;
    float f0 = inv * g0, f1 = inv * g1, f2 = inv * g2;
    acc[0] += a0 * pd[0]; acc[1] += a0 * pd[1]; acc[2] += a0 * pd[2];
    acc[3] += a1 * pd[0]; acc[4] += a1 * pd[1]; acc[5] += a1 * pd[2];
    acc[6] += a2 * pd[0]; acc[7] += a2 * pd[1]; acc[8] += a2 * pd[2];
    acc[9]  += f0 * pd[3]; acc[10] += f0 * pd[4]; acc[11] += f0 * pd[5];
    acc[12] += f1 * pd[3]; acc[13] += f1 * pd[4]; acc[14] += f1 * pd[5];
    acc[15] += f2 * pd[3]; acc[16] += f2 * pd[4]; acc[17] += f2 * pd[5];
    xv = nxt;
  }
#pragma unroll
  for (int k = 0; k < 24; k++) {
    float r = wred_sum(acc[k]);
    if (lane == 0) atomicAdd(&bacc[k], r);
  }
  __syncthreads();

  if (t == 0) {
    float M = bacc[30];
    float Minv = 1.f / fmaxf(M, 1.f);
    bool use_v = (M > 3.f);
    const float Ninv = 1.f / (float)BN;
    float H[3][3], mu[3];
#pragma unroll
    for (int d = 0; d < 3; d++) {
      mu[d] = use_v ? bacc[24 + d] * Minv : bacc[27 + d] * Ninv;
#pragma unroll
      for (int e = 0; e < 3; e++) {
        float hv = bacc[d * 3 + e]     - bacc[24 + d] * bacc[18 + e] * Minv;
        float hf = bacc[9 + d * 3 + e] - bacc[27 + d] * bacc[21 + e] * Ninv;
        H[d][e] = use_v ? hv : hf;
      }
    }
    // K = H^T H
    float K[3][3];
#pragma unroll
    for (int i = 0; i < 3; i++)
#pragma unroll
      for (int j = 0; j < 3; j++) {
        float s_ = 0.f;
#pragma unroll
        for (int k = 0; k < 3; k++) s_ += H[k][i] * H[k][j];
        K[i][j] = s_;
      }
    float V[3][3] = {{1.f,0.f,0.f},{0.f,1.f,0.f},{0.f,0.f,1.f}};
    for (int sw = 0; sw < 8; sw++) { jrot<0,1>(K, V); jrot<0,2>(K, V); jrot<1,2>(K, V); }
    float lam[3] = {K[0][0], K[1][1], K[2][2]};
    cswap<0,1>(lam, V); cswap<1,2>(lam, V); cswap<0,1>(lam, V);

    float v1[3] = {V[0][0], V[1][0], V[2][0]};
    float v2[3] = {V[0][1], V[1][1], V[2][1]};
    float v3[3] = {V[0][2], V[1][2], V[2][2]};
    float u1[3], u2[3], u3[3];
#pragma unroll
    for (int i = 0; i < 3; i++) {
      u1[i] = H[i][0] * v1[0] + H[i][1] * v1[1] + H[i][2] * v1[2];
      u2[i] = H[i][0] * v2[0] + H[i][1] * v2[1] + H[i][2] * v2[2];
    }
    float n1s = u1[0]*u1[0] + u1[1]*u1[1] + u1[2]*u1[2];
    if (n1s > 1e-24f) { float r = 1.f / sqrtf(n1s); u1[0]*=r; u1[1]*=r; u1[2]*=r; }
    else { u1[0] = 1.f; u1[1] = 0.f; u1[2] = 0.f; }
    float d12 = u1[0]*u2[0] + u1[1]*u2[1] + u1[2]*u2[2];
    u2[0] -= d12 * u1[0]; u2[1] -= d12 * u1[1]; u2[2] -= d12 * u1[2];
    float n2s = u2[0]*u2[0] + u2[1]*u2[1] + u2[2]*u2[2];
    if (n2s > 1e-24f) { float r = 1.f / sqrtf(n2s); u2[0]*=r; u2[1]*=r; u2[2]*=r; }
    else {
      float ex = (fabsf(u1[0]) < 0.9f) ? 1.f : 0.f;
      float ey = 1.f - ex;
      // u2 = normalize(cross(u1, e))
      float cx = u1[1]*0.f - u1[2]*ey;
      float cy = u1[2]*ex - u1[0]*0.f;
      float cz = u1[0]*ey - u1[1]*ex;
      float nn = 1.f / sqrtf(cx*cx + cy*cy + cz*cz + 1e-30f);
      u2[0] = cx*nn; u2[1] = cy*nn; u2[2] = cz*nn;
    }
    u3[0] = u1[1]*u2[2] - u1[2]*u2[1];
    u3[1] = u1[2]*u2[0] - u1[0]*u2[2];
    u3[2] = u1[0]*u2[1] - u1[1]*u2[0];
    float detV = v1[0]*(v2[1]*v3[2] - v2[2]*v3[1])
               - v1[1]*(v2[0]*v3[2] - v2[2]*v3[0])
               + v1[2]*(v2[0]*v3[1] - v2[1]*v3[0]);
    float f = (detV < 0.f) ? -1.f : 1.f;
    float R_[3][3];
#pragma unroll
    for (int i = 0; i < 3; i++)
#pragma unroll
      for (int k = 0; k < 3; k++)
        R_[i][k] = v1[i]*u1[k] + v2[i]*u2[k] + f * v3[i]*u3[k];

    float* Rout = out + (size_t)b * 9;
#pragma unroll
    for (int i = 0; i < 3; i++)
#pragma unroll
      for (int k = 0; k < 3; k++)
        Rout[i * 3 + k] = R_[i][k];
    float* Tout = out + (size_t)gridDim.x * 9 + (size_t)b * 3;
#pragma unroll
    for (int i = 0; i < 3; i++)
      Tout[i] = -(R_[i][0]*mu[0] + R_[i][1]*mu[1] + R_[i][2]*mu[2]);
  }
}

extern "C" void kernel_launch(void* const* d_in, const int* in_sizes, int n_in,
                              void* d_out, int out_size, void* d_ws, size_t ws_size,
                              hipStream_t stream) {
  const float* src = (const float*)d_in[0];
  const float* tgt = (const float*)d_in[1];
  const float* scores = (const float*)d_in[2];
  const int* idx0 = (const int*)d_in[3];
  float* out = (float*)d_out;
  int B = in_sizes[0] / (3 * BN);
  hipLaunchKernelGGL(svdhead_kernel, dim3(B), dim3(BLOCK), 0, stream,
                     src, tgt, scores, idx0, out);
}